// Round 2
// baseline (189.462 us; speedup 1.0000x reference)
//
#include <hip/hip_runtime.h>

// Path signature, depth 4: B=32, L=1024, d=8, fp32.
// Levels: S1(8) S2(64) S3(512) S4(4096); sig stride 4680 floats.
//
// Kernel 1 (sig_chunk): one wave per 32-increment chunk (1024 waves), full
//   signature state in registers, lane l=(i*8+j) owns S4[i][j][:][:] etc.
// Kernel 2 (sig_fold8): 4 waves/batch; wave v folds chunk sigs [8v..8v+8)
//   sequentially in registers (7 Chen products), writes partial to slot 8v.
// Kernel 3 (sig_fold4): 1 wave/batch folds the 4 partials, writes d_out.
//
// All fold state lives in VGPRs; __launch_bounds__(..,1) prevents the
// register-cap spilling that made the R1 tree kernel (VGPR_Count=64,
// acc[8][8] spilled to scratch) take 80 us.

#define D 8
#define LPATH 1024
#define NINC 1023
#define BATCH 32
#define CHUNKS 32
#define MSTEP 32
#define SIG_STRIDE 4680
#define OFF2 8
#define OFF3 72
#define OFF4 584

__device__ __forceinline__ float readlane_f(float v, int l) {
  return __builtin_bit_cast(float, __builtin_amdgcn_readlane(__builtin_bit_cast(int, v), l));
}

__device__ __forceinline__ void load8(const float* __restrict__ p, float* dst) {
  float4 lo = *(const float4*)p;
  float4 hi = *(const float4*)(p + 4);
  dst[0] = lo.x; dst[1] = lo.y; dst[2] = lo.z; dst[3] = lo.w;
  dst[4] = hi.x; dst[5] = hi.y; dst[6] = hi.z; dst[7] = hi.w;
}

__device__ __forceinline__ void store8(float* __restrict__ p, const float* src) {
  *(float4*)p       = make_float4(src[0], src[1], src[2], src[3]);
  *(float4*)(p + 4) = make_float4(src[4], src[5], src[6], src[7]);
}

// In-register Chen product: state (s1,s2,s3,s4) = A, multiply on the right by
// signature at Bp. Lane (i,j): s1=A1[i], s2=A2[i][j], s3[k]=A3[i][j][k],
// s4[k][m]=A4[i][j][k][m].
__device__ __forceinline__ void chen_fold(float& s1, float& s2, float s3[D],
                                          float s4[D][D],
                                          const float* __restrict__ Bp,
                                          int i, int j) {
  const int lane = i * 8 + j;
  float b1j = Bp[j];
  float b1i = __shfl(b1j, i, 64);
  float sb1[D];
#pragma unroll
  for (int m = 0; m < D; ++m) sb1[m] = readlane_f(b1j, m);

  float b2own = Bp[OFF2 + lane];
  float b2row[D], b3own[D];
  load8(Bp + OFF2 + j * 8, b2row);        // B2[j][:]
  load8(Bp + OFF3 + lane * 8, b3own);     // B3[i][j][:]

  // C4[i,j,k,m] = A4 + B4 + A3[i,j,k]B1[m] + A2[i,j]B2[k,m] + A1[i]B3[j,k,m]
#pragma unroll
  for (int k = 0; k < D; ++k) {
    float b4[D], b2k[D], b3k[D];
    load8(Bp + OFF4 + lane * 64 + k * 8, b4);
    load8(Bp + OFF2 + k * 8, b2k);
    load8(Bp + OFF3 + (j * 8 + k) * 8, b3k);
#pragma unroll
    for (int m = 0; m < D; ++m) {
      float t = __builtin_fmaf(s3[k], sb1[m], s4[k][m] + b4[m]);
      t = __builtin_fmaf(s2, b2k[m], t);
      s4[k][m] = __builtin_fmaf(s1, b3k[m], t);
    }
  }
  // C3[i,j,k] = A3 + B3 + A1[i]B2[j,k] + A2[i,j]B1[k]
#pragma unroll
  for (int k = 0; k < D; ++k) {
    float t = __builtin_fmaf(s1, b2row[k], s3[k] + b3own[k]);
    s3[k] = __builtin_fmaf(s2, sb1[k], t);
  }
  // C2[i,j] = A2 + B2 + A1[i]B1[j];  C1 = A1 + B1
  s2 = s2 + b2own + s1 * b1j;
  s1 = s1 + b1i;
}

__device__ __forceinline__ void load_sig(const float* __restrict__ Sp, float& s1,
                                         float& s2, float s3[D], float s4[D][D],
                                         int i, int lane) {
  s1 = Sp[i];
  s2 = Sp[OFF2 + lane];
  load8(Sp + OFF3 + lane * 8, s3);
#pragma unroll
  for (int k = 0; k < D; ++k) load8(Sp + OFF4 + lane * 64 + k * 8, s4[k]);
}

__device__ __forceinline__ void store_sig(float* __restrict__ Sp, float s1,
                                          float s2, const float s3[D],
                                          const float s4[D][D], int i, int j,
                                          int lane) {
  if (j == 0) Sp[i] = s1;
  Sp[OFF2 + lane] = s2;
  store8(Sp + OFF3 + lane * 8, s3);
#pragma unroll
  for (int k = 0; k < D; ++k) store8(Sp + OFF4 + lane * 64 + k * 8, s4[k]);
}

// ---------------- Kernel 1: per-chunk signature (one wave per chunk) --------
__global__ __launch_bounds__(256, 1) void sig_chunk(const float* __restrict__ path,
                                                    float* __restrict__ ws) {
  const int gwave = (blockIdx.x * 256 + threadIdx.x) >> 6;  // 0..1023
  const int lane  = threadIdx.x & 63;
  const int b = gwave >> 5;
  const int c = gwave & (CHUNKS - 1);
  const int i = lane >> 3;
  const int j = lane & 7;

  const float* __restrict__ pj = path + (size_t)b * (LPATH * D) + j;
  const int g0 = c * MSTEP;

  float pc = pj[g0 * D];
  int nx = g0 + 1; nx = nx > NINC ? NINC : nx;
  float pnext = pj[nx * D];

  float s1 = 0.f, s2 = 0.f;
  float s3[D];
  float s4[D][D];
#pragma unroll
  for (int k = 0; k < D; ++k) {
    s3[k] = 0.f;
#pragma unroll
    for (int m = 0; m < D; ++m) s4[k][m] = 0.f;
  }

  for (int t = 0; t < MSTEP; ++t) {
    float pn = pnext;
    int n2 = g0 + t + 2; n2 = n2 > NINC ? NINC : n2;  // clamp -> zero inc pad
    pnext = pj[n2 * D];

    float wj = pn - pc;  // increment component j
    pc = pn;
    float wi = __shfl(wj, i, 64);
    float wm[D];
#pragma unroll
    for (int m = 0; m < D; ++m) wm[m] = readlane_f(wj, m);

    // level 4: S4 += S3(x)w + S2(x)w^2/2 + S1(x)w^3/6 + w^4/24 (Horner)
    float b1  = __builtin_fmaf(wi, 0.25f, s1);
    float b2  = __builtin_fmaf(b1, wj * (1.f / 3.f), s2);
    float hb2 = b2 * 0.5f;
    float b3[D];
#pragma unroll
    for (int k = 0; k < D; ++k) b3[k] = __builtin_fmaf(hb2, wm[k], s3[k]);
#pragma unroll
    for (int k = 0; k < D; ++k)
#pragma unroll
      for (int m = 0; m < D; ++m)
        s4[k][m] = __builtin_fmaf(b3[k], wm[m], s4[k][m]);

    // level 3
    float c1 = __builtin_fmaf(wi, (1.f / 3.f), s1);
    float c2 = __builtin_fmaf(c1, wj * 0.5f, s2);
#pragma unroll
    for (int k = 0; k < D; ++k) s3[k] = __builtin_fmaf(c2, wm[k], s3[k]);

    // levels 2, 1
    float d1 = __builtin_fmaf(wi, 0.5f, s1);
    s2 = __builtin_fmaf(d1, wj, s2);
    s1 += wi;
  }

  float* __restrict__ slot = ws + (size_t)(b * CHUNKS + c) * SIG_STRIDE;
  store_sig(slot, s1, s2, s3, s4, i, j, lane);
}

// ------- Kernel 2: each wave folds 8 chunk sigs -> partial in slot 8v -------
__global__ __launch_bounds__(256, 1) void sig_fold8(float* __restrict__ ws) {
  const int b    = blockIdx.x;        // batch
  const int v    = threadIdx.x >> 6;  // wave 0..3
  const int lane = threadIdx.x & 63;
  const int i = lane >> 3;
  const int j = lane & 7;

  float* __restrict__ base = ws + (size_t)(b * CHUNKS + v * 8) * SIG_STRIDE;

  float s1, s2, s3[D], s4[D][D];
  load_sig(base, s1, s2, s3, s4, i, lane);
#pragma unroll
  for (int c = 1; c < 8; ++c)
    chen_fold(s1, s2, s3, s4, base + (size_t)c * SIG_STRIDE, i, j);
  store_sig(base, s1, s2, s3, s4, i, j, lane);
}

// ------- Kernel 3: one wave/batch folds the 4 partials, writes d_out --------
__global__ __launch_bounds__(64, 1) void sig_fold4(const float* __restrict__ ws,
                                                   float* __restrict__ out) {
  const int b    = blockIdx.x;
  const int lane = threadIdx.x & 63;
  const int i = lane >> 3;
  const int j = lane & 7;

  const float* __restrict__ base = ws + (size_t)b * CHUNKS * SIG_STRIDE;

  float s1, s2, s3[D], s4[D][D];
  load_sig(base, s1, s2, s3, s4, i, lane);
#pragma unroll
  for (int c = 1; c < 4; ++c)
    chen_fold(s1, s2, s3, s4, base + (size_t)(c * 8) * SIG_STRIDE, i, j);

  // d_out: S1 (32x8) | S2 (32x64) | S3 (32x512) | S4 (32x4096)
  if (j == 0) out[b * 8 + i] = s1;
  out[256 + b * 64 + lane] = s2;
  store8(out + 2304 + b * 512 + lane * 8, s3);
#pragma unroll
  for (int k = 0; k < D; ++k)
    store8(out + 18688 + b * 4096 + lane * 64 + k * 8, s4[k]);
}

extern "C" void kernel_launch(void* const* d_in, const int* in_sizes, int n_in,
                              void* d_out, int out_size, void* d_ws, size_t ws_size,
                              hipStream_t stream) {
  const float* path = (const float*)d_in[0];
  // d_in[1] = depth (==4), compile-time specialized.
  float* out = (float*)d_out;
  float* ws  = (float*)d_ws;  // 32*32*4680*4 = 19.2 MB

  sig_chunk<<<dim3(256), dim3(256), 0, stream>>>(path, ws);
  sig_fold8<<<dim3(BATCH), dim3(256), 0, stream>>>(ws);
  sig_fold4<<<dim3(BATCH), dim3(64), 0, stream>>>(ws, out);
}

// Round 3
// 132.422 us; speedup vs baseline: 1.4307x; 1.4307x over previous
//
#include <hip/hip_runtime.h>

// Path signature, depth 4: B=32, L=1024, d=8, fp32.
// Levels: S1(8) S2(64) S3(512) S4(4096); sig stride 4680 floats.
//
// Kernel 1 (sig_chunk): one wave per 32-increment chunk (1024 waves), full
//   signature state in registers, lane l=(i*8+j) owns S4[i][j][:][:] etc.
// Kernel 2 (sig_fold8): 4 waves/batch; wave v folds chunk sigs [8v..8v+8)
//   sequentially in registers (7 Chen products), writes partial to slot 8v.
// Kernel 3 (sig_fold4): 1 wave/batch folds the 4 partials, writes d_out.
//
// R2 lesson: '#pragma unroll' on the fold loop inlined 7 chen_folds, the
// compiler hoisted ~350 loads, hit the 256-VGPR architectural cap and spilled
// ~55 MB/dispatch to scratch (FETCH 27.5MB/WRITE 37MB, 119us). The fold loops
// MUST be '#pragma unroll 1' so only one chen_fold body is live at a time.

#define D 8
#define LPATH 1024
#define NINC 1023
#define BATCH 32
#define CHUNKS 32
#define MSTEP 32
#define SIG_STRIDE 4680
#define OFF2 8
#define OFF3 72
#define OFF4 584

__device__ __forceinline__ float readlane_f(float v, int l) {
  return __builtin_bit_cast(float, __builtin_amdgcn_readlane(__builtin_bit_cast(int, v), l));
}

__device__ __forceinline__ void load8(const float* __restrict__ p, float* dst) {
  float4 lo = *(const float4*)p;
  float4 hi = *(const float4*)(p + 4);
  dst[0] = lo.x; dst[1] = lo.y; dst[2] = lo.z; dst[3] = lo.w;
  dst[4] = hi.x; dst[5] = hi.y; dst[6] = hi.z; dst[7] = hi.w;
}

__device__ __forceinline__ void store8(float* __restrict__ p, const float* src) {
  *(float4*)p       = make_float4(src[0], src[1], src[2], src[3]);
  *(float4*)(p + 4) = make_float4(src[4], src[5], src[6], src[7]);
}

// In-register Chen product: state (s1,s2,s3,s4) = A, multiply on the right by
// signature at Bp. Lane (i,j): s1=A1[i], s2=A2[i][j], s3[k]=A3[i][j][k],
// s4[k][m]=A4[i][j][k][m].
__device__ __forceinline__ void chen_fold(float& s1, float& s2, float s3[D],
                                          float s4[D][D],
                                          const float* __restrict__ Bp,
                                          int i, int j) {
  const int lane = i * 8 + j;
  float b1j = Bp[j];
  float b1i = __shfl(b1j, i, 64);
  float sb1[D];
#pragma unroll
  for (int m = 0; m < D; ++m) sb1[m] = readlane_f(b1j, m);

  float b2own = Bp[OFF2 + lane];
  float b2row[D], b3own[D];
  load8(Bp + OFF2 + j * 8, b2row);        // B2[j][:]
  load8(Bp + OFF3 + lane * 8, b3own);     // B3[i][j][:]

  // C4[i,j,k,m] = A4 + B4 + A3[i,j,k]B1[m] + A2[i,j]B2[k,m] + A1[i]B3[j,k,m]
#pragma unroll
  for (int k = 0; k < D; ++k) {
    float b4[D], b2k[D], b3k[D];
    load8(Bp + OFF4 + lane * 64 + k * 8, b4);
    load8(Bp + OFF2 + k * 8, b2k);
    load8(Bp + OFF3 + (j * 8 + k) * 8, b3k);
#pragma unroll
    for (int m = 0; m < D; ++m) {
      float t = __builtin_fmaf(s3[k], sb1[m], s4[k][m] + b4[m]);
      t = __builtin_fmaf(s2, b2k[m], t);
      s4[k][m] = __builtin_fmaf(s1, b3k[m], t);
    }
  }
  // C3[i,j,k] = A3 + B3 + A1[i]B2[j,k] + A2[i,j]B1[k]
#pragma unroll
  for (int k = 0; k < D; ++k) {
    float t = __builtin_fmaf(s1, b2row[k], s3[k] + b3own[k]);
    s3[k] = __builtin_fmaf(s2, sb1[k], t);
  }
  // C2[i,j] = A2 + B2 + A1[i]B1[j];  C1 = A1 + B1
  s2 = s2 + b2own + s1 * b1j;
  s1 = s1 + b1i;
}

__device__ __forceinline__ void load_sig(const float* __restrict__ Sp, float& s1,
                                         float& s2, float s3[D], float s4[D][D],
                                         int i, int lane) {
  s1 = Sp[i];
  s2 = Sp[OFF2 + lane];
  load8(Sp + OFF3 + lane * 8, s3);
#pragma unroll
  for (int k = 0; k < D; ++k) load8(Sp + OFF4 + lane * 64 + k * 8, s4[k]);
}

__device__ __forceinline__ void store_sig(float* __restrict__ Sp, float s1,
                                          float s2, const float s3[D],
                                          const float s4[D][D], int i, int j,
                                          int lane) {
  if (j == 0) Sp[i] = s1;
  Sp[OFF2 + lane] = s2;
  store8(Sp + OFF3 + lane * 8, s3);
#pragma unroll
  for (int k = 0; k < D; ++k) store8(Sp + OFF4 + lane * 64 + k * 8, s4[k]);
}

// ---------------- Kernel 1: per-chunk signature (one wave per chunk) --------
__global__ __launch_bounds__(256, 1) void sig_chunk(const float* __restrict__ path,
                                                    float* __restrict__ ws) {
  const int gwave = (blockIdx.x * 256 + threadIdx.x) >> 6;  // 0..1023
  const int lane  = threadIdx.x & 63;
  const int b = gwave >> 5;
  const int c = gwave & (CHUNKS - 1);
  const int i = lane >> 3;
  const int j = lane & 7;

  const float* __restrict__ pj = path + (size_t)b * (LPATH * D) + j;
  const int g0 = c * MSTEP;

  float pc = pj[g0 * D];
  int nx = g0 + 1; nx = nx > NINC ? NINC : nx;
  float pnext = pj[nx * D];

  float s1 = 0.f, s2 = 0.f;
  float s3[D];
  float s4[D][D];
#pragma unroll
  for (int k = 0; k < D; ++k) {
    s3[k] = 0.f;
#pragma unroll
    for (int m = 0; m < D; ++m) s4[k][m] = 0.f;
  }

#pragma unroll 1
  for (int t = 0; t < MSTEP; ++t) {
    float pn = pnext;
    int n2 = g0 + t + 2; n2 = n2 > NINC ? NINC : n2;  // clamp -> zero inc pad
    pnext = pj[n2 * D];

    float wj = pn - pc;  // increment component j
    pc = pn;
    float wi = __shfl(wj, i, 64);
    float wm[D];
#pragma unroll
    for (int m = 0; m < D; ++m) wm[m] = readlane_f(wj, m);

    // level 4: S4 += S3(x)w + S2(x)w^2/2 + S1(x)w^3/6 + w^4/24 (Horner)
    float b1  = __builtin_fmaf(wi, 0.25f, s1);
    float b2  = __builtin_fmaf(b1, wj * (1.f / 3.f), s2);
    float hb2 = b2 * 0.5f;
    float b3[D];
#pragma unroll
    for (int k = 0; k < D; ++k) b3[k] = __builtin_fmaf(hb2, wm[k], s3[k]);
#pragma unroll
    for (int k = 0; k < D; ++k)
#pragma unroll
      for (int m = 0; m < D; ++m)
        s4[k][m] = __builtin_fmaf(b3[k], wm[m], s4[k][m]);

    // level 3
    float c1 = __builtin_fmaf(wi, (1.f / 3.f), s1);
    float c2 = __builtin_fmaf(c1, wj * 0.5f, s2);
#pragma unroll
    for (int k = 0; k < D; ++k) s3[k] = __builtin_fmaf(c2, wm[k], s3[k]);

    // levels 2, 1
    float d1 = __builtin_fmaf(wi, 0.5f, s1);
    s2 = __builtin_fmaf(d1, wj, s2);
    s1 += wi;
  }

  float* __restrict__ slot = ws + (size_t)(b * CHUNKS + c) * SIG_STRIDE;
  store_sig(slot, s1, s2, s3, s4, i, j, lane);
}

// ------- Kernel 2: each wave folds 8 chunk sigs -> partial in slot 8v -------
__global__ __launch_bounds__(256, 1) void sig_fold8(float* __restrict__ ws) {
  const int b    = blockIdx.x;        // batch
  const int v    = threadIdx.x >> 6;  // wave 0..3
  const int lane = threadIdx.x & 63;
  const int i = lane >> 3;
  const int j = lane & 7;

  float* __restrict__ base = ws + (size_t)(b * CHUNKS + v * 8) * SIG_STRIDE;

  float s1, s2, s3[D], s4[D][D];
  load_sig(base, s1, s2, s3, s4, i, lane);
#pragma unroll 1
  for (int c = 1; c < 8; ++c)
    chen_fold(s1, s2, s3, s4, base + (size_t)c * SIG_STRIDE, i, j);
  store_sig(base, s1, s2, s3, s4, i, j, lane);
}

// ------- Kernel 3: one wave/batch folds the 4 partials, writes d_out --------
__global__ __launch_bounds__(64, 1) void sig_fold4(const float* __restrict__ ws,
                                                   float* __restrict__ out) {
  const int b    = blockIdx.x;
  const int lane = threadIdx.x & 63;
  const int i = lane >> 3;
  const int j = lane & 7;

  const float* __restrict__ base = ws + (size_t)b * CHUNKS * SIG_STRIDE;

  float s1, s2, s3[D], s4[D][D];
  load_sig(base, s1, s2, s3, s4, i, lane);
#pragma unroll 1
  for (int c = 1; c < 4; ++c)
    chen_fold(s1, s2, s3, s4, base + (size_t)(c * 8) * SIG_STRIDE, i, j);

  // d_out: S1 (32x8) | S2 (32x64) | S3 (32x512) | S4 (32x4096)
  if (j == 0) out[b * 8 + i] = s1;
  out[256 + b * 64 + lane] = s2;
  store8(out + 2304 + b * 512 + lane * 8, s3);
#pragma unroll
  for (int k = 0; k < D; ++k)
    store8(out + 18688 + b * 4096 + lane * 64 + k * 8, s4[k]);
}

extern "C" void kernel_launch(void* const* d_in, const int* in_sizes, int n_in,
                              void* d_out, int out_size, void* d_ws, size_t ws_size,
                              hipStream_t stream) {
  const float* path = (const float*)d_in[0];
  // d_in[1] = depth (==4), compile-time specialized.
  float* out = (float*)d_out;
  float* ws  = (float*)d_ws;  // 32*32*4680*4 = 19.2 MB

  sig_chunk<<<dim3(256), dim3(256), 0, stream>>>(path, ws);
  sig_fold8<<<dim3(BATCH), dim3(256), 0, stream>>>(ws);
  sig_fold4<<<dim3(BATCH), dim3(64), 0, stream>>>(ws, out);
}

// Round 4
// 107.470 us; speedup vs baseline: 1.7629x; 1.2322x over previous
//
#include <hip/hip_runtime.h>

// Path signature, depth 4: B=32, L=1024, d=8, fp32.
// Levels: S1(8) S2(64) S3(512) S4(4096); sig stride 4680 floats.
//
// R3 lesson: one wave holding the full 74-float sig state leaves no register
// headroom (compiler allocated 76 VGPRs) -> B-side loads serialize at ~400cyc
// each -> sig_fold8 51us. Fix: 4-way k-slicing. Wave q owns S4[.][.][2q..2q+1][.]
// (16 regs/lane) and redundantly maintains replicated S1,S2,S3 (10 regs/lane,
// identical deterministic arithmetic in all 4 waves -> NO inter-wave comm).
// 4x the waves, ~1/3 the serial work per wave, ~50-110 VGPR pressure.

#define D 8
#define LPATH 1024
#define NINC 1023
#define BATCH 32
#define CHUNKS 32
#define MSTEP 32
#define SIG_STRIDE 4680
#define OFF2 8
#define OFF3 72
#define OFF4 584

__device__ __forceinline__ float readlane_f(float v, int l) {
  return __builtin_bit_cast(float, __builtin_amdgcn_readlane(__builtin_bit_cast(int, v), l));
}

__device__ __forceinline__ void load8(const float* __restrict__ p, float* dst) {
  float4 lo = *(const float4*)p;
  float4 hi = *(const float4*)(p + 4);
  dst[0] = lo.x; dst[1] = lo.y; dst[2] = lo.z; dst[3] = lo.w;
  dst[4] = hi.x; dst[5] = hi.y; dst[6] = hi.z; dst[7] = hi.w;
}

__device__ __forceinline__ void store8(float* __restrict__ p, const float* src) {
  *(float4*)p       = make_float4(src[0], src[1], src[2], src[3]);
  *(float4*)(p + 4) = make_float4(src[4], src[5], src[6], src[7]);
}

// Chen product, k-sliced. Lane (i,j), wave slice k0=2q:
//   s1=S1[i], s2=S2[i][j], s3[k]=S3[i][j][k] (full), s4[t][m]=S4[i][j][k0+t][m].
// A-state in registers; B read from memory at Bp.
__device__ __forceinline__ void chen_fold_slice(float& s1, float& s2,
                                                float s3[D], float s4[2][D],
                                                const float* __restrict__ Bp,
                                                int i, int j, int lane, int k0) {
  float b1j = Bp[j];
  float b1i = __shfl(b1j, i, 64);
  float sb1[D];
#pragma unroll
  for (int m = 0; m < D; ++m) sb1[m] = readlane_f(b1j, m);

  float b2own = Bp[OFF2 + lane];
  float b2row[D], b3own[D];
  load8(Bp + OFF2 + j * 8, b2row);     // B2[j][:]
  load8(Bp + OFF3 + lane * 8, b3own);  // B3[i][j][:]

  float b2k[2][D], b3k[2][D], b4[2][D];
#pragma unroll
  for (int t = 0; t < 2; ++t) {
    load8(Bp + OFF2 + (k0 + t) * 8, b2k[t]);              // B2[k][:]
    load8(Bp + OFF3 + (j * 8 + k0 + t) * 8, b3k[t]);      // B3[j][k][:]
    load8(Bp + OFF4 + lane * 64 + (k0 + t) * 8, b4[t]);   // B4[i][j][k][:]
  }

  // C4[i,j,k,m] = A4 + B4 + A3[i,j,k]B1[m] + A2[i,j]B2[k,m] + A1[i]B3[j,k,m]
#pragma unroll
  for (int t = 0; t < 2; ++t) {
    float a3k = s3[k0 + t];
#pragma unroll
    for (int m = 0; m < D; ++m) {
      float v = __builtin_fmaf(a3k, sb1[m], s4[t][m] + b4[t][m]);
      v = __builtin_fmaf(s2, b2k[t][m], v);
      s4[t][m] = __builtin_fmaf(s1, b3k[t][m], v);
    }
  }
  // C3[i,j,k] = A3 + B3 + A1[i]B2[j,k] + A2[i,j]B1[k]   (full, replicated)
#pragma unroll
  for (int k = 0; k < D; ++k) {
    float v = __builtin_fmaf(s1, b2row[k], s3[k] + b3own[k]);
    s3[k] = __builtin_fmaf(s2, sb1[k], v);
  }
  // C2, C1
  s2 = s2 + b2own + s1 * b1j;
  s1 = s1 + b1i;
}

// ------ Kernel 1: per-chunk signature, 4 waves per chunk (k-sliced) --------
__global__ __launch_bounds__(256) void sig_chunk(const float* __restrict__ path,
                                                 float* __restrict__ ws) {
  const int gw   = (blockIdx.x * 256 + threadIdx.x) >> 6;  // 0..4095
  const int lane = threadIdx.x & 63;
  const int q = gw & 3;                 // k-slice wave
  const int c = (gw >> 2) & (CHUNKS - 1);
  const int b = gw >> 7;
  const int i = lane >> 3;
  const int j = lane & 7;
  const int k0 = q * 2;

  const float* __restrict__ pj = path + (size_t)b * (LPATH * D) + j;
  const int g0 = c * MSTEP;

  float pc = pj[g0 * D];
  int nx = g0 + 1; nx = nx > NINC ? NINC : nx;
  float pnext = pj[nx * D];

  float s1 = 0.f, s2 = 0.f;
  float s3[D] = {0.f, 0.f, 0.f, 0.f, 0.f, 0.f, 0.f, 0.f};
  float s4[2][D];
#pragma unroll
  for (int t = 0; t < 2; ++t)
#pragma unroll
    for (int m = 0; m < D; ++m) s4[t][m] = 0.f;

#pragma unroll 1
  for (int t = 0; t < MSTEP; ++t) {
    float pn = pnext;
    int n2 = g0 + t + 2; n2 = n2 > NINC ? NINC : n2;  // clamp -> zero-inc pad
    pnext = pj[n2 * D];

    float wj = pn - pc;  // increment component j
    pc = pn;
    float wi = __shfl(wj, i, 64);
    float wm[D];
#pragma unroll
    for (int m = 0; m < D; ++m) wm[m] = readlane_f(wj, m);

    // level 4 slice: S4 += S3(x)w + S2(x)w^2/2 + S1(x)w^3/6 + w^4/24 (Horner)
    float h1  = __builtin_fmaf(wi, 0.25f, s1);
    float h2  = __builtin_fmaf(h1, wj * (1.f / 3.f), s2);
    float hb2 = h2 * 0.5f;
    float b3a = __builtin_fmaf(hb2, wm[k0], s3[k0]);
    float b3b = __builtin_fmaf(hb2, wm[k0 + 1], s3[k0 + 1]);
#pragma unroll
    for (int m = 0; m < D; ++m) s4[0][m] = __builtin_fmaf(b3a, wm[m], s4[0][m]);
#pragma unroll
    for (int m = 0; m < D; ++m) s4[1][m] = __builtin_fmaf(b3b, wm[m], s4[1][m]);

    // level 3 (full, replicated)
    float c1 = __builtin_fmaf(wi, (1.f / 3.f), s1);
    float c2 = __builtin_fmaf(c1, wj * 0.5f, s2);
#pragma unroll
    for (int k = 0; k < D; ++k) s3[k] = __builtin_fmaf(c2, wm[k], s3[k]);

    // levels 2, 1
    float d1 = __builtin_fmaf(wi, 0.5f, s1);
    s2 = __builtin_fmaf(d1, wj, s2);
    s1 += wi;
  }

  float* __restrict__ slot = ws + (size_t)(b * CHUNKS + c) * SIG_STRIDE;
  store8(slot + OFF4 + lane * 64 + k0 * 8, s4[0]);
  store8(slot + OFF4 + lane * 64 + (k0 + 1) * 8, s4[1]);
  if (q == 0) {
    if (j == 0) slot[i] = s1;
    slot[OFF2 + lane] = s2;
    store8(slot + OFF3 + lane * 8, s3);
  }
}

// ------ Kernel 2: fold 8 chunk sigs -> partial in slot 8g (4 waves/fold) ----
__global__ __launch_bounds__(256) void sig_fold8(float* __restrict__ ws) {
  const int gw   = (blockIdx.x * 256 + threadIdx.x) >> 6;  // 0..511
  const int lane = threadIdx.x & 63;
  const int q = gw & 3;
  const int g = (gw >> 2) & 3;
  const int b = gw >> 4;
  const int i = lane >> 3;
  const int j = lane & 7;
  const int k0 = q * 2;

  float* __restrict__ base = ws + (size_t)(b * CHUNKS + g * 8) * SIG_STRIDE;

  float s1 = base[i];
  float s2 = base[OFF2 + lane];
  float s3[D], s4[2][D];
  load8(base + OFF3 + lane * 8, s3);
  load8(base + OFF4 + lane * 64 + k0 * 8, s4[0]);
  load8(base + OFF4 + lane * 64 + (k0 + 1) * 8, s4[1]);

#pragma unroll 1
  for (int c = 1; c < 8; ++c)
    chen_fold_slice(s1, s2, s3, s4, base + (size_t)c * SIG_STRIDE, i, j, lane, k0);

  store8(base + OFF4 + lane * 64 + k0 * 8, s4[0]);
  store8(base + OFF4 + lane * 64 + (k0 + 1) * 8, s4[1]);
  if (q == 0) {
    if (j == 0) base[i] = s1;
    base[OFF2 + lane] = s2;
    store8(base + OFF3 + lane * 8, s3);
  }
}

// ------ Kernel 3: fold the 4 partials (4 waves/batch), write d_out ----------
__global__ __launch_bounds__(256) void sig_fold4(const float* __restrict__ ws,
                                                 float* __restrict__ out) {
  const int gw   = (blockIdx.x * 256 + threadIdx.x) >> 6;  // 0..127
  const int lane = threadIdx.x & 63;
  const int q = gw & 3;
  const int b = gw >> 2;
  const int i = lane >> 3;
  const int j = lane & 7;
  const int k0 = q * 2;

  const float* __restrict__ base = ws + (size_t)b * CHUNKS * SIG_STRIDE;

  float s1 = base[i];
  float s2 = base[OFF2 + lane];
  float s3[D], s4[2][D];
  load8(base + OFF3 + lane * 8, s3);
  load8(base + OFF4 + lane * 64 + k0 * 8, s4[0]);
  load8(base + OFF4 + lane * 64 + (k0 + 1) * 8, s4[1]);

#pragma unroll 1
  for (int g = 1; g < 4; ++g)
    chen_fold_slice(s1, s2, s3, s4, base + (size_t)(g * 8) * SIG_STRIDE, i, j,
                    lane, k0);

  // d_out: S1 (32x8) | S2 (32x64) | S3 (32x512) | S4 (32x4096)
  if (q == 0) {
    if (j == 0) out[b * 8 + i] = s1;
    out[256 + b * 64 + lane] = s2;
    store8(out + 2304 + b * 512 + lane * 8, s3);
  }
  store8(out + 18688 + b * 4096 + lane * 64 + k0 * 8, s4[0]);
  store8(out + 18688 + b * 4096 + lane * 64 + (k0 + 1) * 8, s4[1]);
}

extern "C" void kernel_launch(void* const* d_in, const int* in_sizes, int n_in,
                              void* d_out, int out_size, void* d_ws, size_t ws_size,
                              hipStream_t stream) {
  const float* path = (const float*)d_in[0];
  // d_in[1] = depth (==4), compile-time specialized.
  float* out = (float*)d_out;
  float* ws  = (float*)d_ws;  // 32*32*4680*4 = 19.2 MB

  // 32 batches x 32 chunks x 4 k-slice waves = 4096 waves = 1024 blocks
  sig_chunk<<<dim3(1024), dim3(256), 0, stream>>>(path, ws);
  // 32 batches x 4 groups x 4 waves = 512 waves = 128 blocks
  sig_fold8<<<dim3(128), dim3(256), 0, stream>>>(ws);
  // 32 batches x 4 waves = 128 waves = 32 blocks
  sig_fold4<<<dim3(32), dim3(256), 0, stream>>>(ws, out);
}